// Round 4
// baseline (675.256 us; speedup 1.0000x reference)
//
#include <hip/hip_runtime.h>
#include <math.h>

#define N0 16
#define N1 200
#define N2 200
#define NPIX (N1 * N2)            // 40000
#define NVOX (N0 * NPIX)          // 640000
#define NUM_RAD 223
#define NUM_PHI 190
#define NUM_T 351
#define NSINO (N0 * NUM_PHI * NUM_RAD)  // 677920
#define ORG1F (-199.0f)
#define ORG2F (-199.0f)

// ---------------- constants: replicate numpy linspace / cos / gaussian ----------------
__global__ void init_consts(float* __restrict__ cosb, float* __restrict__ sinb,
                            float* __restrict__ rvb, float* __restrict__ gwb) {
    int t = threadIdx.x;
    const double PI = 3.14159265358979311599796346854418516159;
    if (t < NUM_PHI) {
        double step = PI / 190.0;             // np.linspace(0, pi, 190, endpoint=False)
        float phif = (float)((double)t * step);
        cosb[t] = (float)cos((double)phif);   // np.cos on float32 input
        sinb[t] = (float)sin((double)phif);
    }
    if (t < NUM_RAD) {
        double step = 400.0 / 222.0;          // np.linspace(-200, 200, 223)
        float rv = (float)(-200.0 + (double)t * step);
        if (t == NUM_RAD - 1) rv = 200.0f;    // linspace endpoint fixup
        rvb[t] = rv;
    }
    if (t == 0) {
        double sig = 4.5 / (2.35 * 2.0);
        double g[9], ssum = 0.0;
        for (int k = 0; k < 9; ++k) { double d = (double)(k - 4) / sig; g[k] = exp(-0.5 * d * d); ssum += g[k]; }
        for (int k = 0; k < 9; ++k) gwb[k] = (float)(g[k] / ssum);
    }
}

// ---------------- separable gaussian, forward (symmetric pad) ----------------
__global__ void smooth_fwd(const float* __restrict__ in, float* __restrict__ out,
                           const float* __restrict__ gwb, int n, int stride) {
    int e = blockIdx.x * 256 + threadIdx.x;
    if (e >= NVOX) return;
    int a = (e / stride) % n;
    int base = e - a * stride;
    float sum = 0.f;
#pragma unroll
    for (int k = 0; k < 9; ++k) {
        int q = a + k - 4;
        q = (q < 0) ? (-1 - q) : ((q >= n) ? (2 * n - 1 - q) : q);
        sum = __fadd_rn(sum, __fmul_rn(gwb[k], in[base + q * stride]));
    }
    out[e] = sum;
}

// axis-2 pass that also writes the per-slice transposed copy outT[i0][i2][i1]
__global__ void smooth_fwd2_dual(const float* __restrict__ in, float* __restrict__ out,
                                 float* __restrict__ outT, const float* __restrict__ gwb) {
    int e = blockIdx.x * 256 + threadIdx.x;
    if (e >= NVOX) return;
    int a = e % N2;                 // i2
    int base = e - a;
    float sum = 0.f;
#pragma unroll
    for (int k = 0; k < 9; ++k) {
        int q = a + k - 4;
        q = (q < 0) ? (-1 - q) : ((q >= N2) ? (2 * N2 - 1 - q) : q);
        sum = __fadd_rn(sum, __fmul_rn(gwb[k], in[base + q]));
    }
    out[e] = sum;
    int i0 = e / NPIX;
    int rem = e - i0 * NPIX;
    int i1 = rem / N2;              // row
    outT[i0 * NPIX + a * N1 + i1] = sum;
}

// ---------------- separable gaussian, adjoint (pad-transpose fold) ----------------
__device__ __forceinline__ float adj_u(const float* __restrict__ in, const float* __restrict__ gwb,
                                       int base, int stride, int n, int j) {
    float r = 0.f;
#pragma unroll
    for (int k = 0; k < 9; ++k) {
        int i = j - k;
        if (i >= 0 && i < n) r = __fadd_rn(r, __fmul_rn(gwb[k], in[base + i * stride]));
    }
    return r;
}

__global__ void smooth_adj(const float* __restrict__ in, float* __restrict__ out,
                           const float* __restrict__ gwb, int n, int stride) {
    int e = blockIdx.x * 256 + threadIdx.x;
    if (e >= NVOX) return;
    int a = (e / stride) % n;
    int base = e - a * stride;
    float v = adj_u(in, gwb, base, stride, n, a + 4);
    if (a < 4)      v = __fadd_rn(v, adj_u(in, gwb, base, stride, n, 3 - a));
    if (a >= n - 4) v = __fadd_rn(v, adj_u(in, gwb, base, stride, n, 2 * n + 3 - a));
    out[e] = v;
}

// final axis-0 adjoint pass fused with  out = x * v / sens
__global__ void smooth_adj0_final(const float* __restrict__ in, const float* __restrict__ x,
                                  const float* __restrict__ sens, const float* __restrict__ gwb,
                                  float* __restrict__ out) {
    int e = blockIdx.x * 256 + threadIdx.x;
    if (e >= NVOX) return;
    int a = e / NPIX;
    int base = e - a * NPIX;
    float v = adj_u(in, gwb, base, NPIX, N0, a + 4);
    if (a < 4)  v = __fadd_rn(v, adj_u(in, gwb, base, NPIX, N0, 3 - a));
    if (a >= 12) v = __fadd_rn(v, adj_u(in, gwb, base, NPIX, N0, 35 - a));
    out[e] = __fdiv_rn(__fmul_rn(x[e], v), sens[e]);
}

// ---------------- forward projection + ratio, fused ----------------
// block (256,2): thread.x = radial bin r, thread.y = t-half. blockIdx.y = slice
// quad (4 slices/thread -> 16 independent loads per iteration). Halves combine
// via LDS; half 0 does the ratio epilogue. Per-phi layout selection keeps
// r-adjacent threads contiguous in memory for every angle.
__global__ void project_ratio(const float* __restrict__ simg, const float* __restrict__ simgT,
                              const float* __restrict__ data,
                              const float* __restrict__ contam, const float* __restrict__ mult,
                              const float* __restrict__ cosb, const float* __restrict__ sinb,
                              const float* __restrict__ rvb, float* __restrict__ zt) {
    int phi = blockIdx.x;
    int i0 = blockIdx.y * 4;
    int r = threadIdx.x;
    int half = threadIdx.y;
    bool active = (r < NUM_RAD);

    __shared__ float part[4][256];

    float sums[4] = {0.f, 0.f, 0.f, 0.f};
    float c = cosb[phi], sp = sinb[phi];

    // layout select: make the r-varying pixel direction contiguous
    bool useT = fabsf(sp) > fabsf(c);
    int sI = useT ? 1 : N2;
    int sJ = useT ? N1 : 1;
    const float* sl0 = (useT ? simgT : simg) + i0 * NPIX;

    if (active) {
        float rv = rvb[r];
        float A = __fmul_rn(rv, -sp);   // RV * (-s)
        float B = __fmul_rn(rv, c);     // RV * c

        // conservative valid-t window
        float tlo = -350.f, thi = 350.f;
        bool empty = false;
        if (fabsf(c) > 1e-6f) {
            float a0 = (-199.f - A) / c, b0 = (199.f - A) / c;
            tlo = fmaxf(tlo, fminf(a0, b0)); thi = fminf(thi, fmaxf(a0, b0));
        } else if (fabsf(A) > 199.5f) empty = true;
        if (fabsf(sp) > 1e-6f) {
            float a0 = (-199.f - B) / sp, b0 = (199.f - B) / sp;
            tlo = fmaxf(tlo, fminf(a0, b0)); thi = fminf(thi, fmaxf(a0, b0));
        } else if (fabsf(B) > 199.5f) empty = true;

        int klo = max(0, (int)floorf((tlo + 350.f) * 0.5f) - 1);
        int khi = min(NUM_T - 1, (int)ceilf((thi + 350.f) * 0.5f) + 1);

        if (!empty && klo <= khi) {
            int kmid = (klo + khi + 1) >> 1;
            int kbeg = half ? kmid : klo;
            int kend = half ? khi : (kmid - 1);
#pragma unroll 2
            for (int k = kbeg; k <= kend; ++k) {
                float tv = (float)(2 * k - 350);
                float ix = __fmul_rn(__fsub_rn(__fadd_rn(A, __fmul_rn(tv, c)), ORG1F), 0.5f);
                float iy = __fmul_rn(__fsub_rn(__fadd_rn(B, __fmul_rn(tv, sp)), ORG2F), 0.5f);
                bool valid = (ix >= 0.f && ix <= 199.f && iy >= 0.f && iy <= 199.f);
                float fx = floorf(ix), fy = floorf(iy);
                int ii = (int)fx, jj = (int)fy;
                float fi = ix - fx, fj = iy - fy;
                int ii0 = min(max(ii, 0), 199), jj0 = min(max(jj, 0), 199);
                int ii1 = min(ii0 + 1, 199),   jj1 = min(jj0 + 1, 199);
                float w00 = (1.f - fi) * (1.f - fj), w10 = fi * (1.f - fj);
                float w01 = (1.f - fi) * fj,         w11 = fi * fj;
                int o00 = ii0 * sI + jj0 * sJ, o10 = ii1 * sI + jj0 * sJ;
                int o01 = ii0 * sI + jj1 * sJ, o11 = ii1 * sI + jj1 * sJ;
                // batched independent loads (16) ...
                float v00[4], v10[4], v01[4], v11[4];
#pragma unroll
                for (int s = 0; s < 4; ++s) {
                    const float* sl = sl0 + s * NPIX;
                    v00[s] = sl[o00]; v10[s] = sl[o10];
                    v01[s] = sl[o01]; v11[s] = sl[o11];
                }
                // ... then FMA batch
                float m = valid ? 1.f : 0.f;
#pragma unroll
                for (int s = 0; s < 4; ++s) {
                    float v = w00 * v00[s] + w10 * v10[s] + w01 * v01[s] + w11 * v11[s];
                    sums[s] = __fadd_rn(sums[s], __fmul_rn(v, m));
                }
            }
        }
    }

    if (half == 1) {
#pragma unroll
        for (int s = 0; s < 4; ++s) part[s][r] = sums[s];
    }
    __syncthreads();
    if (half == 0 && active) {
#pragma unroll
        for (int s = 0; s < 4; ++s) {
            float proj = __fmul_rn(__fadd_rn(sums[s], part[s][r]), 2.0f);  // * STEP
            int sl = i0 + s;
            int idx = (sl * NUM_PHI + phi) * NUM_RAD + r;
            float ex = __fadd_rn(__fmul_rn(mult[idx], proj), contam[idx]);
            float zval = __fmul_rn(mult[idx], __fdiv_rn(data[idx], ex));
            zt[(phi * NUM_RAD + r) * N0 + sl] = zval;
        }
    }
}

// ---------------- adjoint projection, gather form ----------------
// thread = (pixel, phi-chunk of 19). Accumulates all 16 slices, atomicAdd into bp[i0][pix].
__global__ void backproject(const float* __restrict__ zt, const float* __restrict__ cosb,
                            const float* __restrict__ sinb, const float* __restrict__ rvb,
                            float* __restrict__ bp) {
    int g = blockIdx.x * 256 + threadIdx.x;
    if (g >= NPIX * 10) return;
    int pc = g / NPIX;
    int pix = g - pc * NPIX;
    int i1 = pix / N2;
    int i2 = pix - i1 * N2;
    float X1 = 2.f * (float)i1 - 199.f;   // ORG1 + i1*VOX (exact)
    float X2 = 2.f * (float)i2 - 199.f;
    float acc[N0];
#pragma unroll
    for (int i0 = 0; i0 < N0; ++i0) acc[i0] = 0.f;

    int p_end = pc * 19 + 19;
    for (int p = pc * 19; p < p_end; ++p) {
        float c = cosb[p], sp = sinb[p];
        float tp = c * X1 + sp * X2;      // candidate location only (precision uncritical)
        float rp = c * X2 - sp * X1;
        int j0 = (int)floorf((rp + 200.f) * 0.555f);   // 222/400
        int k0 = (int)floorf((tp + 350.f) * 0.5f);
        for (int dj = -1; dj <= 2; ++dj) {
            int j = j0 + dj;
            if (j < 0 || j > NUM_RAD - 1) continue;
            float rv = rvb[j];
            float A = __fmul_rn(rv, -sp);
            float B = __fmul_rn(rv, c);
            float w = 0.f;
            for (int dk = -1; dk <= 2; ++dk) {
                int k = k0 + dk;
                if (k < 0 || k > NUM_T - 1) continue;
                float tv = (float)(2 * k - 350);
                // EXACT same op sequence as forward -> identical ix/iy/validity
                float ix = __fmul_rn(__fsub_rn(__fadd_rn(A, __fmul_rn(tv, c)), ORG1F), 0.5f);
                float iy = __fmul_rn(__fsub_rn(__fadd_rn(B, __fmul_rn(tv, sp)), ORG2F), 0.5f);
                if (!(ix >= 0.f && ix <= 199.f && iy >= 0.f && iy <= 199.f)) continue;
                float fx = floorf(ix), fy = floorf(iy);
                int ii = (int)fx, jj = (int)fy;
                float fi = ix - fx, fj = iy - fy;
                float wx = (ii == i1) ? (1.f - fi) : ((ii + 1 == i1) ? fi : 0.f);
                if (wx == 0.f) continue;
                float wy = (jj == i2) ? (1.f - fj) : ((jj + 1 == i2) ? fj : 0.f);
                w += wx * wy;
            }
            if (w != 0.f) {
                const float* zp = zt + (p * NUM_RAD + j) * N0;
#pragma unroll
                for (int i0 = 0; i0 < N0; ++i0) acc[i0] += w * zp[i0];
            }
        }
    }
#pragma unroll
    for (int i0 = 0; i0 < N0; ++i0)
        atomicAdd(&bp[i0 * NPIX + pix], acc[i0] * 2.0f);  // * STEP
}

extern "C" void kernel_launch(void* const* d_in, const int* in_sizes, int n_in,
                              void* d_out, int out_size, void* d_ws, size_t ws_size,
                              hipStream_t stream) {
    const float* x      = (const float*)d_in[0];
    const float* data   = (const float*)d_in[1];
    const float* contam = (const float*)d_in[2];
    const float* mult   = (const float*)d_in[3];
    const float* sens   = (const float*)d_in[4];
    float* out = (float*)d_out;

    float* W    = (float*)d_ws;
    float* s    = W;                       // 640000
    float* tmp  = W + NVOX;                // 640000
    float* bp   = W + 2 * NVOX;            // 640000
    float* sT   = W + 3 * NVOX;            // 640000 (transposed smoothed image)
    float* zt   = W + 4 * NVOX;            // 677920
    float* cosb = W + 4 * NVOX + NSINO;
    float* sinb = cosb + NUM_PHI;
    float* rvb  = sinb + NUM_PHI;
    float* gwb  = rvb + NUM_RAD;

    hipLaunchKernelGGL(init_consts, dim3(1), dim3(256), 0, stream, cosb, sinb, rvb, gwb);

    // gauss3 forward: x -> s (axis0), s -> tmp (axis1), tmp -> {s, sT} (axis2 dual-store)
    int nb = (NVOX + 255) / 256;
    hipLaunchKernelGGL(smooth_fwd, dim3(nb), dim3(256), 0, stream, x,   s,   gwb, N0, NPIX);
    hipLaunchKernelGGL(smooth_fwd, dim3(nb), dim3(256), 0, stream, s,   tmp, gwb, N1, N2);
    hipLaunchKernelGGL(smooth_fwd2_dual, dim3(nb), dim3(256), 0, stream, tmp, s, sT, gwb);

    // forward project + ratio (writes zt): 4 slices/thread, 2 t-halves/block
    hipLaunchKernelGGL(project_ratio, dim3(NUM_PHI, N0 / 4), dim3(256, 2), 0, stream,
                       s, sT, data, contam, mult, cosb, sinb, rvb, zt);

    // backproject (gather) into bp
    hipMemsetAsync(bp, 0, NVOX * sizeof(float), stream);
    int nb2 = (NPIX * 10 + 255) / 256;
    hipLaunchKernelGGL(backproject, dim3(nb2), dim3(256), 0, stream, zt, cosb, sinb, rvb, bp);

    // gauss3 adjoint: bp -> tmp (axis2^T), tmp -> bp (axis1^T), bp -> out (axis0^T fused final)
    hipLaunchKernelGGL(smooth_adj, dim3(nb), dim3(256), 0, stream, bp,  tmp, gwb, N2, 1);
    hipLaunchKernelGGL(smooth_adj, dim3(nb), dim3(256), 0, stream, tmp, bp,  gwb, N1, N2);
    hipLaunchKernelGGL(smooth_adj0_final, dim3(nb), dim3(256), 0, stream, bp, x, sens, gwb, out);
}

// Round 5
// 458.015 us; speedup vs baseline: 1.4743x; 1.4743x over previous
//
#include <hip/hip_runtime.h>
#include <math.h>

#define N0 16
#define N1 200
#define N2 200
#define NPIX (N1 * N2)            // 40000
#define NVOX (N0 * NPIX)          // 640000
#define NUM_RAD 223
#define NUM_PHI 190
#define NUM_T 351
#define NSINO (N0 * NUM_PHI * NUM_RAD)  // 677920
#define ORG1F (-199.0f)
#define ORG2F (-199.0f)
#define QSTRIDE (201 * 201 * 4)   // padded quad-interleaved slice group

// ---------------- constants: replicate numpy linspace / cos / gaussian ----------------
__global__ void init_consts(float* __restrict__ cosb, float* __restrict__ sinb,
                            float* __restrict__ rvb, float* __restrict__ gwb) {
    int t = threadIdx.x;
    const double PI = 3.14159265358979311599796346854418516159;
    if (t < NUM_PHI) {
        double step = PI / 190.0;             // np.linspace(0, pi, 190, endpoint=False)
        float phif = (float)((double)t * step);
        cosb[t] = (float)cos((double)phif);   // np.cos on float32 input
        sinb[t] = (float)sin((double)phif);
    }
    if (t < NUM_RAD) {
        double step = 400.0 / 222.0;          // np.linspace(-200, 200, 223)
        float rv = (float)(-200.0 + (double)t * step);
        if (t == NUM_RAD - 1) rv = 200.0f;    // linspace endpoint fixup
        rvb[t] = rv;
    }
    if (t == 0) {
        double sig = 4.5 / (2.35 * 2.0);
        double g[9], ssum = 0.0;
        for (int k = 0; k < 9; ++k) { double d = (double)(k - 4) / sig; g[k] = exp(-0.5 * d * d); ssum += g[k]; }
        for (int k = 0; k < 9; ++k) gwb[k] = (float)(g[k] / ssum);
    }
}

// ---------------- separable gaussian, forward (symmetric pad) ----------------
__global__ void smooth_fwd(const float* __restrict__ in, float* __restrict__ out,
                           const float* __restrict__ gwb, int n, int stride) {
    int e = blockIdx.x * 256 + threadIdx.x;
    if (e >= NVOX) return;
    int a = (e / stride) % n;
    int base = e - a * stride;
    float sum = 0.f;
#pragma unroll
    for (int k = 0; k < 9; ++k) {
        int q = a + k - 4;
        q = (q < 0) ? (-1 - q) : ((q >= n) ? (2 * n - 1 - q) : q);
        sum = __fadd_rn(sum, __fmul_rn(gwb[k], in[base + q * stride]));
    }
    out[e] = sum;
}

// axis-2 pass writing quad-interleaved padded layouts:
//   P [q][i1][i2][s]  and  PT[q][i2][i1][s],  201x201 with edge replication.
__global__ void smooth_fwd2_quad(const float* __restrict__ in, float* __restrict__ P,
                                 float* __restrict__ PT, const float* __restrict__ gwb) {
    int e = blockIdx.x * 256 + threadIdx.x;
    if (e >= NVOX) return;
    int i2 = e % N2;
    int base = e - i2;
    float sum = 0.f;
#pragma unroll
    for (int k = 0; k < 9; ++k) {
        int q = i2 + k - 4;
        q = (q < 0) ? (-1 - q) : ((q >= N2) ? (2 * N2 - 1 - q) : q);
        sum = __fadd_rn(sum, __fmul_rn(gwb[k], in[base + q]));
    }
    int i0 = e / NPIX;
    int rem = e - i0 * NPIX;
    int i1 = rem / N2;
    int qd = i0 >> 2, s = i0 & 3;
    float* Pq  = P  + qd * QSTRIDE;
    float* PTq = PT + qd * QSTRIDE;
    bool e1 = (i1 == 199), e2 = (i2 == 199);
    Pq[(i1 * 201 + i2) * 4 + s] = sum;
    if (e2) Pq[(i1 * 201 + 200) * 4 + s] = sum;
    if (e1) Pq[(200 * 201 + i2) * 4 + s] = sum;
    if (e1 && e2) Pq[(200 * 201 + 200) * 4 + s] = sum;
    PTq[(i2 * 201 + i1) * 4 + s] = sum;
    if (e1) PTq[(i2 * 201 + 200) * 4 + s] = sum;
    if (e2) PTq[(200 * 201 + i1) * 4 + s] = sum;
    if (e1 && e2) PTq[(200 * 201 + 200) * 4 + s] = sum;
}

// ---------------- separable gaussian, adjoint (pad-transpose fold) ----------------
__device__ __forceinline__ float adj_u(const float* __restrict__ in, const float* __restrict__ gwb,
                                       int base, int stride, int n, int j) {
    float r = 0.f;
#pragma unroll
    for (int k = 0; k < 9; ++k) {
        int i = j - k;
        if (i >= 0 && i < n) r = __fadd_rn(r, __fmul_rn(gwb[k], in[base + i * stride]));
    }
    return r;
}

__global__ void smooth_adj(const float* __restrict__ in, float* __restrict__ out,
                           const float* __restrict__ gwb, int n, int stride) {
    int e = blockIdx.x * 256 + threadIdx.x;
    if (e >= NVOX) return;
    int a = (e / stride) % n;
    int base = e - a * stride;
    float v = adj_u(in, gwb, base, stride, n, a + 4);
    if (a < 4)      v = __fadd_rn(v, adj_u(in, gwb, base, stride, n, 3 - a));
    if (a >= n - 4) v = __fadd_rn(v, adj_u(in, gwb, base, stride, n, 2 * n + 3 - a));
    out[e] = v;
}

// final axis-0 adjoint pass fused with  out = x * v / sens
__global__ void smooth_adj0_final(const float* __restrict__ in, const float* __restrict__ x,
                                  const float* __restrict__ sens, const float* __restrict__ gwb,
                                  float* __restrict__ out) {
    int e = blockIdx.x * 256 + threadIdx.x;
    if (e >= NVOX) return;
    int a = e / NPIX;
    int base = e - a * NPIX;
    float v = adj_u(in, gwb, base, NPIX, N0, a + 4);
    if (a < 4)  v = __fadd_rn(v, adj_u(in, gwb, base, NPIX, N0, 3 - a));
    if (a >= 12) v = __fadd_rn(v, adj_u(in, gwb, base, NPIX, N0, 35 - a));
    out[e] = __fdiv_rn(__fmul_rn(x[e], v), sens[e]);
}

// ---------------- forward projection + ratio, fused ----------------
// block (256,2): x = radial bin r, y = t-half; blockIdx = (phi, quad).
// Quad-interleaved padded image: one float4 load = same pixel, 4 slices.
// 4 float4 loads per t-sample (was 16 scalar). Per-phi layout selection keeps
// r-adjacent lanes contiguous. Halves combine via LDS; half 0 does the ratio.
__global__ void project_ratio(const float* __restrict__ P, const float* __restrict__ PT,
                              const float* __restrict__ data,
                              const float* __restrict__ contam, const float* __restrict__ mult,
                              const float* __restrict__ cosb, const float* __restrict__ sinb,
                              const float* __restrict__ rvb, float* __restrict__ zt) {
    int phi = blockIdx.x;
    int qd = blockIdx.y;
    int i0 = qd * 4;
    int r = threadIdx.x;
    int half = threadIdx.y;
    bool active = (r < NUM_RAD);

    __shared__ float part[4][256];

    float sums[4] = {0.f, 0.f, 0.f, 0.f};
    float c = cosb[phi], sp = sinb[phi];

    bool useT = fabsf(sp) > fabsf(c);
    const float* basep = (useT ? PT : P) + qd * QSTRIDE;
    int dI = useT ? 4 : 804;   // float-offset step for ii+1
    int dJ = useT ? 804 : 4;   // float-offset step for jj+1

    if (active) {
        float rv = rvb[r];
        float A = __fmul_rn(rv, -sp);   // RV * (-s)
        float B = __fmul_rn(rv, c);     // RV * c

        // conservative valid-t window
        float tlo = -350.f, thi = 350.f;
        bool empty = false;
        if (fabsf(c) > 1e-6f) {
            float a0 = (-199.f - A) / c, b0 = (199.f - A) / c;
            tlo = fmaxf(tlo, fminf(a0, b0)); thi = fminf(thi, fmaxf(a0, b0));
        } else if (fabsf(A) > 199.5f) empty = true;
        if (fabsf(sp) > 1e-6f) {
            float a0 = (-199.f - B) / sp, b0 = (199.f - B) / sp;
            tlo = fmaxf(tlo, fminf(a0, b0)); thi = fminf(thi, fmaxf(a0, b0));
        } else if (fabsf(B) > 199.5f) empty = true;

        int klo = max(0, (int)floorf((tlo + 350.f) * 0.5f) - 1);
        int khi = min(NUM_T - 1, (int)ceilf((thi + 350.f) * 0.5f) + 1);

        if (!empty && klo <= khi) {
            int kmid = (klo + khi + 1) >> 1;
            int kbeg = half ? kmid : klo;
            int kend = half ? khi : (kmid - 1);
#pragma unroll 4
            for (int k = kbeg; k <= kend; ++k) {
                float tv = (float)(2 * k - 350);
                float ix = __fmul_rn(__fsub_rn(__fadd_rn(A, __fmul_rn(tv, c)), ORG1F), 0.5f);
                float iy = __fmul_rn(__fsub_rn(__fadd_rn(B, __fmul_rn(tv, sp)), ORG2F), 0.5f);
                bool valid = (ix >= 0.f && ix <= 199.f && iy >= 0.f && iy <= 199.f);
                float fx = floorf(ix), fy = floorf(iy);
                int ii = (int)fx, jj = (int)fy;
                float fi = ix - fx, fj = iy - fy;
                int ii0 = min(max(ii, 0), 199), jj0 = min(max(jj, 0), 199);
                int rowi = useT ? jj0 : ii0;
                int coli = useT ? ii0 : jj0;
                int o = (rowi * 201 + coli) * 4;
                float4 L00 = *(const float4*)(basep + o);
                float4 L10 = *(const float4*)(basep + o + dI);
                float4 L01 = *(const float4*)(basep + o + dJ);
                float4 L11 = *(const float4*)(basep + o + dI + dJ);
                float w00 = (1.f - fi) * (1.f - fj), w10 = fi * (1.f - fj);
                float w01 = (1.f - fi) * fj,         w11 = fi * fj;
                float m = valid ? 1.f : 0.f;
                float v0 = w00 * L00.x + w10 * L10.x + w01 * L01.x + w11 * L11.x;
                float v1 = w00 * L00.y + w10 * L10.y + w01 * L01.y + w11 * L11.y;
                float v2 = w00 * L00.z + w10 * L10.z + w01 * L01.z + w11 * L11.z;
                float v3 = w00 * L00.w + w10 * L10.w + w01 * L01.w + w11 * L11.w;
                sums[0] = __fadd_rn(sums[0], __fmul_rn(v0, m));
                sums[1] = __fadd_rn(sums[1], __fmul_rn(v1, m));
                sums[2] = __fadd_rn(sums[2], __fmul_rn(v2, m));
                sums[3] = __fadd_rn(sums[3], __fmul_rn(v3, m));
            }
        }
    }

    if (half == 1) {
#pragma unroll
        for (int s = 0; s < 4; ++s) part[s][r] = sums[s];
    }
    __syncthreads();
    if (half == 0 && active) {
#pragma unroll
        for (int s = 0; s < 4; ++s) {
            float proj = __fmul_rn(__fadd_rn(sums[s], part[s][r]), 2.0f);  // * STEP
            int sl = i0 + s;
            int idx = (sl * NUM_PHI + phi) * NUM_RAD + r;
            float ex = __fadd_rn(__fmul_rn(mult[idx], proj), contam[idx]);
            float zval = __fmul_rn(mult[idx], __fdiv_rn(data[idx], ex));
            zt[(phi * NUM_RAD + r) * N0 + sl] = zval;
        }
    }
}

// ---------------- adjoint projection, gather form ----------------
// thread = (pixel, phi-chunk of 19). Accumulates all 16 slices, atomicAdd into bp[i0][pix].
__global__ void backproject(const float* __restrict__ zt, const float* __restrict__ cosb,
                            const float* __restrict__ sinb, const float* __restrict__ rvb,
                            float* __restrict__ bp) {
    int g = blockIdx.x * 256 + threadIdx.x;
    if (g >= NPIX * 10) return;
    int pc = g / NPIX;
    int pix = g - pc * NPIX;
    int i1 = pix / N2;
    int i2 = pix - i1 * N2;
    float X1 = 2.f * (float)i1 - 199.f;   // ORG1 + i1*VOX (exact)
    float X2 = 2.f * (float)i2 - 199.f;
    float acc[N0];
#pragma unroll
    for (int i0 = 0; i0 < N0; ++i0) acc[i0] = 0.f;

    int p_end = pc * 19 + 19;
    for (int p = pc * 19; p < p_end; ++p) {
        float c = cosb[p], sp = sinb[p];
        float tp = c * X1 + sp * X2;      // candidate location only (precision uncritical)
        float rp = c * X2 - sp * X1;
        int j0 = (int)floorf((rp + 200.f) * 0.555f);   // 222/400
        int k0 = (int)floorf((tp + 350.f) * 0.5f);
        for (int dj = -1; dj <= 2; ++dj) {
            int j = j0 + dj;
            if (j < 0 || j > NUM_RAD - 1) continue;
            float rv = rvb[j];
            float A = __fmul_rn(rv, -sp);
            float B = __fmul_rn(rv, c);
            float w = 0.f;
            for (int dk = -1; dk <= 2; ++dk) {
                int k = k0 + dk;
                if (k < 0 || k > NUM_T - 1) continue;
                float tv = (float)(2 * k - 350);
                // EXACT same op sequence as forward -> identical ix/iy/validity
                float ix = __fmul_rn(__fsub_rn(__fadd_rn(A, __fmul_rn(tv, c)), ORG1F), 0.5f);
                float iy = __fmul_rn(__fsub_rn(__fadd_rn(B, __fmul_rn(tv, sp)), ORG2F), 0.5f);
                if (!(ix >= 0.f && ix <= 199.f && iy >= 0.f && iy <= 199.f)) continue;
                float fx = floorf(ix), fy = floorf(iy);
                int ii = (int)fx, jj = (int)fy;
                float fi = ix - fx, fj = iy - fy;
                float wx = (ii == i1) ? (1.f - fi) : ((ii + 1 == i1) ? fi : 0.f);
                if (wx == 0.f) continue;
                float wy = (jj == i2) ? (1.f - fj) : ((jj + 1 == i2) ? fj : 0.f);
                w += wx * wy;
            }
            if (w != 0.f) {
                const float* zp = zt + (p * NUM_RAD + j) * N0;
#pragma unroll
                for (int i0 = 0; i0 < N0; ++i0) acc[i0] += w * zp[i0];
            }
        }
    }
#pragma unroll
    for (int i0 = 0; i0 < N0; ++i0)
        atomicAdd(&bp[i0 * NPIX + pix], acc[i0] * 2.0f);  // * STEP
}

extern "C" void kernel_launch(void* const* d_in, const int* in_sizes, int n_in,
                              void* d_out, int out_size, void* d_ws, size_t ws_size,
                              hipStream_t stream) {
    const float* x      = (const float*)d_in[0];
    const float* data   = (const float*)d_in[1];
    const float* contam = (const float*)d_in[2];
    const float* mult   = (const float*)d_in[3];
    const float* sens   = (const float*)d_in[4];
    float* out = (float*)d_out;

    float* W    = (float*)d_ws;
    float* s    = W;                        // 640000 (smoothed; later reused as bp)
    float* tmp  = W + NVOX;                 // 640000
    float* bp2  = W + 2 * NVOX;             // 640000
    float* zt   = W + 3 * NVOX;             // 677920
    float* P    = W + 3 * NVOX + NSINO;     // 646416
    float* PT   = P + 4 * QSTRIDE;          // 646416
    float* cosb = PT + 4 * QSTRIDE;
    float* sinb = cosb + NUM_PHI;
    float* rvb  = sinb + NUM_PHI;
    float* gwb  = rvb + NUM_RAD;

    hipLaunchKernelGGL(init_consts, dim3(1), dim3(256), 0, stream, cosb, sinb, rvb, gwb);

    // gauss3 forward: x -> s (axis0), s -> tmp (axis1), tmp -> {P, PT} (axis2 quad dual-store)
    int nb = (NVOX + 255) / 256;
    hipLaunchKernelGGL(smooth_fwd, dim3(nb), dim3(256), 0, stream, x,   s,   gwb, N0, NPIX);
    hipLaunchKernelGGL(smooth_fwd, dim3(nb), dim3(256), 0, stream, s,   tmp, gwb, N1, N2);
    hipLaunchKernelGGL(smooth_fwd2_quad, dim3(nb), dim3(256), 0, stream, tmp, P, PT, gwb);

    // forward project + ratio (writes zt): 4 slices/thread via float4, 2 t-halves/block
    hipLaunchKernelGGL(project_ratio, dim3(NUM_PHI, N0 / 4), dim3(256, 2), 0, stream,
                       P, PT, data, contam, mult, cosb, sinb, rvb, zt);

    // backproject (gather) into bp (reuse s)
    float* bp = s;
    hipMemsetAsync(bp, 0, NVOX * sizeof(float), stream);
    int nb2 = (NPIX * 10 + 255) / 256;
    hipLaunchKernelGGL(backproject, dim3(nb2), dim3(256), 0, stream, zt, cosb, sinb, rvb, bp);

    // gauss3 adjoint: bp -> tmp (axis2^T), tmp -> bp2 (axis1^T), bp2 -> out (axis0^T fused final)
    hipLaunchKernelGGL(smooth_adj, dim3(nb), dim3(256), 0, stream, bp,  tmp, gwb, N2, 1);
    hipLaunchKernelGGL(smooth_adj, dim3(nb), dim3(256), 0, stream, tmp, bp2, gwb, N1, N2);
    hipLaunchKernelGGL(smooth_adj0_final, dim3(nb), dim3(256), 0, stream, bp2, x, sens, gwb, out);
}

// Round 6
// 383.541 us; speedup vs baseline: 1.7606x; 1.1942x over previous
//
#include <hip/hip_runtime.h>
#include <math.h>

#define N0 16
#define N1 200
#define N2 200
#define NPIX (N1 * N2)            // 40000
#define NVOX (N0 * NPIX)          // 640000
#define NUM_RAD 223
#define NUM_PHI 190
#define NUM_T 351
#define NSINO (N0 * NUM_PHI * NUM_RAD)  // 677920
#define ORG1F (-199.0f)
#define ORG2F (-199.0f)
#define QSTRIDE (201 * 201 * 4)   // padded quad-interleaved slice group
#define BP_CHUNK 10
#define BP_NCH 19                 // 190 = 19 * 10

// ---------------- constants: replicate numpy linspace / cos / gaussian ----------------
__global__ void init_consts(float* __restrict__ cosb, float* __restrict__ sinb,
                            float* __restrict__ rvb, float* __restrict__ gwb) {
    int t = threadIdx.x;
    const double PI = 3.14159265358979311599796346854418516159;
    if (t < NUM_PHI) {
        double step = PI / 190.0;             // np.linspace(0, pi, 190, endpoint=False)
        float phif = (float)((double)t * step);
        cosb[t] = (float)cos((double)phif);   // np.cos on float32 input
        sinb[t] = (float)sin((double)phif);
    }
    if (t < NUM_RAD) {
        double step = 400.0 / 222.0;          // np.linspace(-200, 200, 223)
        float rv = (float)(-200.0 + (double)t * step);
        if (t == NUM_RAD - 1) rv = 200.0f;    // linspace endpoint fixup
        rvb[t] = rv;
    }
    if (t == 0) {
        double sig = 4.5 / (2.35 * 2.0);
        double g[9], ssum = 0.0;
        for (int k = 0; k < 9; ++k) { double d = (double)(k - 4) / sig; g[k] = exp(-0.5 * d * d); ssum += g[k]; }
        for (int k = 0; k < 9; ++k) gwb[k] = (float)(g[k] / ssum);
    }
}

// ---------------- separable gaussian, forward (symmetric pad) ----------------
__global__ void smooth_fwd(const float* __restrict__ in, float* __restrict__ out,
                           const float* __restrict__ gwb, int n, int stride) {
    int e = blockIdx.x * 256 + threadIdx.x;
    if (e >= NVOX) return;
    int a = (e / stride) % n;
    int base = e - a * stride;
    float sum = 0.f;
#pragma unroll
    for (int k = 0; k < 9; ++k) {
        int q = a + k - 4;
        q = (q < 0) ? (-1 - q) : ((q >= n) ? (2 * n - 1 - q) : q);
        sum = __fadd_rn(sum, __fmul_rn(gwb[k], in[base + q * stride]));
    }
    out[e] = sum;
}

// axis-2 pass writing quad-interleaved padded layouts:
//   P [q][i1][i2][s]  and  PT[q][i2][i1][s],  201x201 with edge replication.
__global__ void smooth_fwd2_quad(const float* __restrict__ in, float* __restrict__ P,
                                 float* __restrict__ PT, const float* __restrict__ gwb) {
    int e = blockIdx.x * 256 + threadIdx.x;
    if (e >= NVOX) return;
    int i2 = e % N2;
    int base = e - i2;
    float sum = 0.f;
#pragma unroll
    for (int k = 0; k < 9; ++k) {
        int q = i2 + k - 4;
        q = (q < 0) ? (-1 - q) : ((q >= N2) ? (2 * N2 - 1 - q) : q);
        sum = __fadd_rn(sum, __fmul_rn(gwb[k], in[base + q]));
    }
    int i0 = e / NPIX;
    int rem = e - i0 * NPIX;
    int i1 = rem / N2;
    int qd = i0 >> 2, s = i0 & 3;
    float* Pq  = P  + qd * QSTRIDE;
    float* PTq = PT + qd * QSTRIDE;
    bool e1 = (i1 == 199), e2 = (i2 == 199);
    Pq[(i1 * 201 + i2) * 4 + s] = sum;
    if (e2) Pq[(i1 * 201 + 200) * 4 + s] = sum;
    if (e1) Pq[(200 * 201 + i2) * 4 + s] = sum;
    if (e1 && e2) Pq[(200 * 201 + 200) * 4 + s] = sum;
    PTq[(i2 * 201 + i1) * 4 + s] = sum;
    if (e1) PTq[(i2 * 201 + 200) * 4 + s] = sum;
    if (e2) PTq[(200 * 201 + i1) * 4 + s] = sum;
    if (e1 && e2) PTq[(200 * 201 + 200) * 4 + s] = sum;
}

// ---------------- separable gaussian, adjoint (pad-transpose fold) ----------------
__device__ __forceinline__ float adj_u(const float* __restrict__ in, const float* __restrict__ gwb,
                                       int base, int stride, int n, int j) {
    float r = 0.f;
#pragma unroll
    for (int k = 0; k < 9; ++k) {
        int i = j - k;
        if (i >= 0 && i < n) r = __fadd_rn(r, __fmul_rn(gwb[k], in[base + i * stride]));
    }
    return r;
}

__global__ void smooth_adj(const float* __restrict__ in, float* __restrict__ out,
                           const float* __restrict__ gwb, int n, int stride) {
    int e = blockIdx.x * 256 + threadIdx.x;
    if (e >= NVOX) return;
    int a = (e / stride) % n;
    int base = e - a * stride;
    float v = adj_u(in, gwb, base, stride, n, a + 4);
    if (a < 4)      v = __fadd_rn(v, adj_u(in, gwb, base, stride, n, 3 - a));
    if (a >= n - 4) v = __fadd_rn(v, adj_u(in, gwb, base, stride, n, 2 * n + 3 - a));
    out[e] = v;
}

// final axis-0 adjoint pass fused with  out = x * v / sens
__global__ void smooth_adj0_final(const float* __restrict__ in, const float* __restrict__ x,
                                  const float* __restrict__ sens, const float* __restrict__ gwb,
                                  float* __restrict__ out) {
    int e = blockIdx.x * 256 + threadIdx.x;
    if (e >= NVOX) return;
    int a = e / NPIX;
    int base = e - a * NPIX;
    float v = adj_u(in, gwb, base, NPIX, N0, a + 4);
    if (a < 4)  v = __fadd_rn(v, adj_u(in, gwb, base, NPIX, N0, 3 - a));
    if (a >= 12) v = __fadd_rn(v, adj_u(in, gwb, base, NPIX, N0, 35 - a));
    out[e] = __fdiv_rn(__fmul_rn(x[e], v), sens[e]);
}

// geometry for one t-sample (shared by pipeline stages)
#define GEOM(K, W00, W10, W01, W11, M, O)                                        \
    {                                                                            \
        float tv = (float)(2 * (K) - 350);                                       \
        float ix = __fmul_rn(__fsub_rn(__fadd_rn(A, __fmul_rn(tv, c)), ORG1F), 0.5f); \
        float iy = __fmul_rn(__fsub_rn(__fadd_rn(B, __fmul_rn(tv, sp)), ORG2F), 0.5f); \
        bool valid = (ix >= 0.f && ix <= 199.f && iy >= 0.f && iy <= 199.f);     \
        float fx = floorf(ix), fy = floorf(iy);                                  \
        int ii = (int)fx, jj = (int)fy;                                          \
        float fi = ix - fx, fj = iy - fy;                                        \
        int ii0 = min(max(ii, 0), 199), jj0 = min(max(jj, 0), 199);              \
        int rowi = useT ? jj0 : ii0;                                             \
        int coli = useT ? ii0 : jj0;                                             \
        O = (rowi * 201 + coli) * 4;                                             \
        W00 = (1.f - fi) * (1.f - fj); W10 = fi * (1.f - fj);                    \
        W01 = (1.f - fi) * fj;         W11 = fi * fj;                            \
        M = valid ? 1.f : 0.f;                                                   \
    }

// ---------------- forward projection + ratio, fused ----------------
// block (256,2): x = radial bin r, y = t-half; blockIdx = (phi, quad).
// Quad-interleaved padded image: one float4 load = same pixel, 4 slices.
// Explicitly software-pipelined: issue loads for k+1 before consuming k.
__global__ __launch_bounds__(512, 2)
void project_ratio(const float* __restrict__ P, const float* __restrict__ PT,
                   const float* __restrict__ data,
                   const float* __restrict__ contam, const float* __restrict__ mult,
                   const float* __restrict__ cosb, const float* __restrict__ sinb,
                   const float* __restrict__ rvb, float* __restrict__ zt) {
    int phi = blockIdx.x;
    int qd = blockIdx.y;
    int i0 = qd * 4;
    int r = threadIdx.x;
    int half = threadIdx.y;
    bool active = (r < NUM_RAD);

    __shared__ float part[4][256];

    float sums[4] = {0.f, 0.f, 0.f, 0.f};
    float c = cosb[phi], sp = sinb[phi];

    bool useT = fabsf(sp) > fabsf(c);
    const float* basep = (useT ? PT : P) + qd * QSTRIDE;
    int dI = useT ? 4 : 804;   // float-offset step for ii+1
    int dJ = useT ? 804 : 4;   // float-offset step for jj+1

    if (active) {
        float rv = rvb[r];
        float A = __fmul_rn(rv, -sp);   // RV * (-s)
        float B = __fmul_rn(rv, c);     // RV * c

        // conservative valid-t window
        float tlo = -350.f, thi = 350.f;
        bool empty = false;
        if (fabsf(c) > 1e-6f) {
            float a0 = (-199.f - A) / c, b0 = (199.f - A) / c;
            tlo = fmaxf(tlo, fminf(a0, b0)); thi = fminf(thi, fmaxf(a0, b0));
        } else if (fabsf(A) > 199.5f) empty = true;
        if (fabsf(sp) > 1e-6f) {
            float a0 = (-199.f - B) / sp, b0 = (199.f - B) / sp;
            tlo = fmaxf(tlo, fminf(a0, b0)); thi = fminf(thi, fmaxf(a0, b0));
        } else if (fabsf(B) > 199.5f) empty = true;

        int klo = max(0, (int)floorf((tlo + 350.f) * 0.5f) - 1);
        int khi = min(NUM_T - 1, (int)ceilf((thi + 350.f) * 0.5f) + 1);

        if (!empty && klo <= khi) {
            int kmid = (klo + khi + 1) >> 1;
            int kbeg = half ? kmid : klo;
            int kend = half ? khi : (kmid - 1);
            if (kbeg <= kend) {
                float w00, w10, w01, w11, m;
                int o;
                GEOM(kbeg, w00, w10, w01, w11, m, o);
                float4 L00 = *(const float4*)(basep + o);
                float4 L10 = *(const float4*)(basep + o + dI);
                float4 L01 = *(const float4*)(basep + o + dJ);
                float4 L11 = *(const float4*)(basep + o + dI + dJ);
#pragma unroll 2
                for (int k = kbeg; k < kend; ++k) {
                    float nw00, nw10, nw01, nw11, nm;
                    int no;
                    GEOM(k + 1, nw00, nw10, nw01, nw11, nm, no);
                    float4 N00 = *(const float4*)(basep + no);
                    float4 N10 = *(const float4*)(basep + no + dI);
                    float4 N01 = *(const float4*)(basep + no + dJ);
                    float4 N11 = *(const float4*)(basep + no + dI + dJ);
                    // consume current
                    float v0 = w00 * L00.x + w10 * L10.x + w01 * L01.x + w11 * L11.x;
                    float v1 = w00 * L00.y + w10 * L10.y + w01 * L01.y + w11 * L11.y;
                    float v2 = w00 * L00.z + w10 * L10.z + w01 * L01.z + w11 * L11.z;
                    float v3 = w00 * L00.w + w10 * L10.w + w01 * L01.w + w11 * L11.w;
                    sums[0] = __fadd_rn(sums[0], __fmul_rn(v0, m));
                    sums[1] = __fadd_rn(sums[1], __fmul_rn(v1, m));
                    sums[2] = __fadd_rn(sums[2], __fmul_rn(v2, m));
                    sums[3] = __fadd_rn(sums[3], __fmul_rn(v3, m));
                    // rotate
                    w00 = nw00; w10 = nw10; w01 = nw01; w11 = nw11; m = nm;
                    L00 = N00; L10 = N10; L01 = N01; L11 = N11;
                }
                // tail
                float v0 = w00 * L00.x + w10 * L10.x + w01 * L01.x + w11 * L11.x;
                float v1 = w00 * L00.y + w10 * L10.y + w01 * L01.y + w11 * L11.y;
                float v2 = w00 * L00.z + w10 * L10.z + w01 * L01.z + w11 * L11.z;
                float v3 = w00 * L00.w + w10 * L10.w + w01 * L01.w + w11 * L11.w;
                sums[0] = __fadd_rn(sums[0], __fmul_rn(v0, m));
                sums[1] = __fadd_rn(sums[1], __fmul_rn(v1, m));
                sums[2] = __fadd_rn(sums[2], __fmul_rn(v2, m));
                sums[3] = __fadd_rn(sums[3], __fmul_rn(v3, m));
            }
        }
    }

    if (half == 1) {
#pragma unroll
        for (int s = 0; s < 4; ++s) part[s][r] = sums[s];
    }
    __syncthreads();
    if (half == 0 && active) {
#pragma unroll
        for (int s = 0; s < 4; ++s) {
            float proj = __fmul_rn(__fadd_rn(sums[s], part[s][r]), 2.0f);  // * STEP
            int sl = i0 + s;
            int idx = (sl * NUM_PHI + phi) * NUM_RAD + r;
            float ex = __fadd_rn(__fmul_rn(mult[idx], proj), contam[idx]);
            float zval = __fmul_rn(mult[idx], __fdiv_rn(data[idx], ex));
            zt[(phi * NUM_RAD + r) * N0 + sl] = zval;
        }
    }
}

// ---------------- adjoint projection, gather form ----------------
// thread = (pixel, phi-chunk of 10). p is wave-uniform; z reads are float4.
__global__ void backproject(const float* __restrict__ zt, const float* __restrict__ cosb,
                            const float* __restrict__ sinb, const float* __restrict__ rvb,
                            float* __restrict__ bp) {
    int g = blockIdx.x * 256 + threadIdx.x;
    if (g >= NPIX * BP_NCH) return;
    int pc = g / NPIX;
    int pix = g - pc * NPIX;
    int i1 = pix / N2;
    int i2 = pix - i1 * N2;
    float X1 = 2.f * (float)i1 - 199.f;   // ORG1 + i1*VOX (exact)
    float X2 = 2.f * (float)i2 - 199.f;
    float acc[N0];
#pragma unroll
    for (int i0 = 0; i0 < N0; ++i0) acc[i0] = 0.f;

    int p_end = pc * BP_CHUNK + BP_CHUNK;
    for (int p = pc * BP_CHUNK; p < p_end; ++p) {
        float c = cosb[p], sp = sinb[p];
        float tp = c * X1 + sp * X2;      // candidate location only (precision uncritical)
        float rp = c * X2 - sp * X1;
        int j0 = (int)floorf((rp + 200.f) * 0.555f);   // 222/400
        int k0 = (int)floorf((tp + 350.f) * 0.5f);
        for (int dj = -1; dj <= 2; ++dj) {
            int j = j0 + dj;
            if (j < 0 || j > NUM_RAD - 1) continue;
            float rv = rvb[j];
            float A = __fmul_rn(rv, -sp);
            float B = __fmul_rn(rv, c);
            float w = 0.f;
            for (int dk = -1; dk <= 2; ++dk) {
                int k = k0 + dk;
                if (k < 0 || k > NUM_T - 1) continue;
                float tv = (float)(2 * k - 350);
                // EXACT same op sequence as forward -> identical ix/iy/validity
                float ix = __fmul_rn(__fsub_rn(__fadd_rn(A, __fmul_rn(tv, c)), ORG1F), 0.5f);
                float iy = __fmul_rn(__fsub_rn(__fadd_rn(B, __fmul_rn(tv, sp)), ORG2F), 0.5f);
                if (!(ix >= 0.f && ix <= 199.f && iy >= 0.f && iy <= 199.f)) continue;
                float fx = floorf(ix), fy = floorf(iy);
                int ii = (int)fx, jj = (int)fy;
                float fi = ix - fx, fj = iy - fy;
                float wx = (ii == i1) ? (1.f - fi) : ((ii + 1 == i1) ? fi : 0.f);
                if (wx == 0.f) continue;
                float wy = (jj == i2) ? (1.f - fj) : ((jj + 1 == i2) ? fj : 0.f);
                w += wx * wy;
            }
            if (w != 0.f) {
                const float4* zp4 = (const float4*)(zt + (p * NUM_RAD + j) * N0);
                float4 z0 = zp4[0], z1 = zp4[1], z2 = zp4[2], z3 = zp4[3];
                acc[0]  += w * z0.x;  acc[1]  += w * z0.y;
                acc[2]  += w * z0.z;  acc[3]  += w * z0.w;
                acc[4]  += w * z1.x;  acc[5]  += w * z1.y;
                acc[6]  += w * z1.z;  acc[7]  += w * z1.w;
                acc[8]  += w * z2.x;  acc[9]  += w * z2.y;
                acc[10] += w * z2.z;  acc[11] += w * z2.w;
                acc[12] += w * z3.x;  acc[13] += w * z3.y;
                acc[14] += w * z3.z;  acc[15] += w * z3.w;
            }
        }
    }
#pragma unroll
    for (int i0 = 0; i0 < N0; ++i0)
        atomicAdd(&bp[i0 * NPIX + pix], acc[i0] * 2.0f);  // * STEP
}

extern "C" void kernel_launch(void* const* d_in, const int* in_sizes, int n_in,
                              void* d_out, int out_size, void* d_ws, size_t ws_size,
                              hipStream_t stream) {
    const float* x      = (const float*)d_in[0];
    const float* data   = (const float*)d_in[1];
    const float* contam = (const float*)d_in[2];
    const float* mult   = (const float*)d_in[3];
    const float* sens   = (const float*)d_in[4];
    float* out = (float*)d_out;

    float* W    = (float*)d_ws;
    float* s    = W;                        // 640000 (smoothed; later reused as bp)
    float* tmp  = W + NVOX;                 // 640000
    float* bp2  = W + 2 * NVOX;             // 640000
    float* zt   = W + 3 * NVOX;             // 677920
    float* P    = W + 3 * NVOX + NSINO;     // 646416
    float* PT   = P + 4 * QSTRIDE;          // 646416
    float* cosb = PT + 4 * QSTRIDE;
    float* sinb = cosb + NUM_PHI;
    float* rvb  = sinb + NUM_PHI;
    float* gwb  = rvb + NUM_RAD;

    hipLaunchKernelGGL(init_consts, dim3(1), dim3(256), 0, stream, cosb, sinb, rvb, gwb);

    // gauss3 forward: x -> s (axis0), s -> tmp (axis1), tmp -> {P, PT} (axis2 quad dual-store)
    int nb = (NVOX + 255) / 256;
    hipLaunchKernelGGL(smooth_fwd, dim3(nb), dim3(256), 0, stream, x,   s,   gwb, N0, NPIX);
    hipLaunchKernelGGL(smooth_fwd, dim3(nb), dim3(256), 0, stream, s,   tmp, gwb, N1, N2);
    hipLaunchKernelGGL(smooth_fwd2_quad, dim3(nb), dim3(256), 0, stream, tmp, P, PT, gwb);

    // forward project + ratio (writes zt): 4 slices/thread via float4, 2 t-halves/block
    hipLaunchKernelGGL(project_ratio, dim3(NUM_PHI, N0 / 4), dim3(256, 2), 0, stream,
                       P, PT, data, contam, mult, cosb, sinb, rvb, zt);

    // backproject (gather) into bp (reuse s)
    float* bp = s;
    hipMemsetAsync(bp, 0, NVOX * sizeof(float), stream);
    int nb2 = (NPIX * BP_NCH + 255) / 256;
    hipLaunchKernelGGL(backproject, dim3(nb2), dim3(256), 0, stream, zt, cosb, sinb, rvb, bp);

    // gauss3 adjoint: bp -> tmp (axis2^T), tmp -> bp2 (axis1^T), bp2 -> out (axis0^T fused final)
    hipLaunchKernelGGL(smooth_adj, dim3(nb), dim3(256), 0, stream, bp,  tmp, gwb, N2, 1);
    hipLaunchKernelGGL(smooth_adj, dim3(nb), dim3(256), 0, stream, tmp, bp2, gwb, N1, N2);
    hipLaunchKernelGGL(smooth_adj0_final, dim3(nb), dim3(256), 0, stream, bp2, x, sens, gwb, out);
}

// Round 7
// 364.061 us; speedup vs baseline: 1.8548x; 1.0535x over previous
//
#include <hip/hip_runtime.h>
#include <math.h>

#define N0 16
#define N1 200
#define N2 200
#define NPIX (N1 * N2)            // 40000
#define NVOX (N0 * NPIX)          // 640000
#define NUM_RAD 223
#define NUM_PHI 190
#define NUM_T 351
#define NSINO (N0 * NUM_PHI * NUM_RAD)  // 677920
#define ORG1F (-199.0f)
#define ORG2F (-199.0f)
#define QSTRIDE (201 * 201 * 4)   // padded quad-interleaved slice group
#define BP_CHUNK 10
#define BP_NCH 19                 // 190 = 19 * 10

// ---------------- constants: replicate numpy linspace / cos / gaussian ----------------
__global__ void init_consts(float* __restrict__ cosb, float* __restrict__ sinb,
                            float* __restrict__ rvb, float* __restrict__ gwb) {
    int t = threadIdx.x;
    const double PI = 3.14159265358979311599796346854418516159;
    if (t < NUM_PHI) {
        double step = PI / 190.0;             // np.linspace(0, pi, 190, endpoint=False)
        float phif = (float)((double)t * step);
        cosb[t] = (float)cos((double)phif);   // np.cos on float32 input
        sinb[t] = (float)sin((double)phif);
    }
    if (t < NUM_RAD) {
        double step = 400.0 / 222.0;          // np.linspace(-200, 200, 223)
        float rv = (float)(-200.0 + (double)t * step);
        if (t == NUM_RAD - 1) rv = 200.0f;    // linspace endpoint fixup
        rvb[t] = rv;
    }
    if (t == 0) {
        double sig = 4.5 / (2.35 * 2.0);
        double g[9], ssum = 0.0;
        for (int k = 0; k < 9; ++k) { double d = (double)(k - 4) / sig; g[k] = exp(-0.5 * d * d); ssum += g[k]; }
        for (int k = 0; k < 9; ++k) gwb[k] = (float)(g[k] / ssum);
    }
}

// ---------------- separable gaussian, forward (symmetric pad) ----------------
__global__ void smooth_fwd(const float* __restrict__ in, float* __restrict__ out,
                           const float* __restrict__ gwb, int n, int stride) {
    int e = blockIdx.x * 256 + threadIdx.x;
    if (e >= NVOX) return;
    int a = (e / stride) % n;
    int base = e - a * stride;
    float sum = 0.f;
#pragma unroll
    for (int k = 0; k < 9; ++k) {
        int q = a + k - 4;
        q = (q < 0) ? (-1 - q) : ((q >= n) ? (2 * n - 1 - q) : q);
        sum = __fadd_rn(sum, __fmul_rn(gwb[k], in[base + q * stride]));
    }
    out[e] = sum;
}

// axis-2 pass writing quad-interleaved padded layouts:
//   P [q][i1][i2][s]  and  PT[q][i2][i1][s],  201x201 with edge replication.
__global__ void smooth_fwd2_quad(const float* __restrict__ in, float* __restrict__ P,
                                 float* __restrict__ PT, const float* __restrict__ gwb) {
    int e = blockIdx.x * 256 + threadIdx.x;
    if (e >= NVOX) return;
    int i2 = e % N2;
    int base = e - i2;
    float sum = 0.f;
#pragma unroll
    for (int k = 0; k < 9; ++k) {
        int q = i2 + k - 4;
        q = (q < 0) ? (-1 - q) : ((q >= N2) ? (2 * N2 - 1 - q) : q);
        sum = __fadd_rn(sum, __fmul_rn(gwb[k], in[base + q]));
    }
    int i0 = e / NPIX;
    int rem = e - i0 * NPIX;
    int i1 = rem / N2;
    int qd = i0 >> 2, s = i0 & 3;
    float* Pq  = P  + qd * QSTRIDE;
    float* PTq = PT + qd * QSTRIDE;
    bool e1 = (i1 == 199), e2 = (i2 == 199);
    Pq[(i1 * 201 + i2) * 4 + s] = sum;
    if (e2) Pq[(i1 * 201 + 200) * 4 + s] = sum;
    if (e1) Pq[(200 * 201 + i2) * 4 + s] = sum;
    if (e1 && e2) Pq[(200 * 201 + 200) * 4 + s] = sum;
    PTq[(i2 * 201 + i1) * 4 + s] = sum;
    if (e1) PTq[(i2 * 201 + 200) * 4 + s] = sum;
    if (e2) PTq[(200 * 201 + i1) * 4 + s] = sum;
    if (e1 && e2) PTq[(200 * 201 + 200) * 4 + s] = sum;
}

// ---------------- separable gaussian, adjoint (pad-transpose fold) ----------------
__device__ __forceinline__ float adj_u(const float* __restrict__ in, const float* __restrict__ gwb,
                                       int base, int stride, int n, int j) {
    float r = 0.f;
#pragma unroll
    for (int k = 0; k < 9; ++k) {
        int i = j - k;
        if (i >= 0 && i < n) r = __fadd_rn(r, __fmul_rn(gwb[k], in[base + i * stride]));
    }
    return r;
}

__global__ void smooth_adj(const float* __restrict__ in, float* __restrict__ out,
                           const float* __restrict__ gwb, int n, int stride) {
    int e = blockIdx.x * 256 + threadIdx.x;
    if (e >= NVOX) return;
    int a = (e / stride) % n;
    int base = e - a * stride;
    float v = adj_u(in, gwb, base, stride, n, a + 4);
    if (a < 4)      v = __fadd_rn(v, adj_u(in, gwb, base, stride, n, 3 - a));
    if (a >= n - 4) v = __fadd_rn(v, adj_u(in, gwb, base, stride, n, 2 * n + 3 - a));
    out[e] = v;
}

// final axis-0 adjoint pass fused with  out = x * v / sens
__global__ void smooth_adj0_final(const float* __restrict__ in, const float* __restrict__ x,
                                  const float* __restrict__ sens, const float* __restrict__ gwb,
                                  float* __restrict__ out) {
    int e = blockIdx.x * 256 + threadIdx.x;
    if (e >= NVOX) return;
    int a = e / NPIX;
    int base = e - a * NPIX;
    float v = adj_u(in, gwb, base, NPIX, N0, a + 4);
    if (a < 4)  v = __fadd_rn(v, adj_u(in, gwb, base, NPIX, N0, 3 - a));
    if (a >= 12) v = __fadd_rn(v, adj_u(in, gwb, base, NPIX, N0, 35 - a));
    out[e] = __fdiv_rn(__fmul_rn(x[e], v), sens[e]);
}

// geometry for one t-sample (shared by pipeline stages)
#define GEOM(K, W00, W10, W01, W11, M, O)                                        \
    {                                                                            \
        float tv = (float)(2 * (K) - 350);                                       \
        float ix = __fmul_rn(__fsub_rn(__fadd_rn(A, __fmul_rn(tv, c)), ORG1F), 0.5f); \
        float iy = __fmul_rn(__fsub_rn(__fadd_rn(B, __fmul_rn(tv, sp)), ORG2F), 0.5f); \
        bool valid = (ix >= 0.f && ix <= 199.f && iy >= 0.f && iy <= 199.f);     \
        float fx = floorf(ix), fy = floorf(iy);                                  \
        int ii = (int)fx, jj = (int)fy;                                          \
        float fi = ix - fx, fj = iy - fy;                                        \
        int ii0 = min(max(ii, 0), 199), jj0 = min(max(jj, 0), 199);              \
        int rowi = useT ? jj0 : ii0;                                             \
        int coli = useT ? ii0 : jj0;                                             \
        O = (rowi * 201 + coli) * 4;                                             \
        W00 = (1.f - fi) * (1.f - fj); W10 = fi * (1.f - fj);                    \
        W01 = (1.f - fi) * fj;         W11 = fi * fj;                            \
        M = valid ? 1.f : 0.f;                                                   \
    }

// ---------------- forward projection + ratio, fused ----------------
__global__ __launch_bounds__(512, 2)
void project_ratio(const float* __restrict__ P, const float* __restrict__ PT,
                   const float* __restrict__ data,
                   const float* __restrict__ contam, const float* __restrict__ mult,
                   const float* __restrict__ cosb, const float* __restrict__ sinb,
                   const float* __restrict__ rvb, float* __restrict__ zt) {
    int phi = blockIdx.x;
    int qd = blockIdx.y;
    int i0 = qd * 4;
    int r = threadIdx.x;
    int half = threadIdx.y;
    bool active = (r < NUM_RAD);

    __shared__ float part[4][256];

    float sums[4] = {0.f, 0.f, 0.f, 0.f};
    float c = cosb[phi], sp = sinb[phi];

    bool useT = fabsf(sp) > fabsf(c);
    const float* basep = (useT ? PT : P) + qd * QSTRIDE;
    int dI = useT ? 4 : 804;   // float-offset step for ii+1
    int dJ = useT ? 804 : 4;   // float-offset step for jj+1

    if (active) {
        float rv = rvb[r];
        float A = __fmul_rn(rv, -sp);   // RV * (-s)
        float B = __fmul_rn(rv, c);     // RV * c

        // conservative valid-t window
        float tlo = -350.f, thi = 350.f;
        bool empty = false;
        if (fabsf(c) > 1e-6f) {
            float a0 = (-199.f - A) / c, b0 = (199.f - A) / c;
            tlo = fmaxf(tlo, fminf(a0, b0)); thi = fminf(thi, fmaxf(a0, b0));
        } else if (fabsf(A) > 199.5f) empty = true;
        if (fabsf(sp) > 1e-6f) {
            float a0 = (-199.f - B) / sp, b0 = (199.f - B) / sp;
            tlo = fmaxf(tlo, fminf(a0, b0)); thi = fminf(thi, fmaxf(a0, b0));
        } else if (fabsf(B) > 199.5f) empty = true;

        int klo = max(0, (int)floorf((tlo + 350.f) * 0.5f) - 1);
        int khi = min(NUM_T - 1, (int)ceilf((thi + 350.f) * 0.5f) + 1);

        if (!empty && klo <= khi) {
            int kmid = (klo + khi + 1) >> 1;
            int kbeg = half ? kmid : klo;
            int kend = half ? khi : (kmid - 1);
            if (kbeg <= kend) {
                float w00, w10, w01, w11, m;
                int o;
                GEOM(kbeg, w00, w10, w01, w11, m, o);
                float4 L00 = *(const float4*)(basep + o);
                float4 L10 = *(const float4*)(basep + o + dI);
                float4 L01 = *(const float4*)(basep + o + dJ);
                float4 L11 = *(const float4*)(basep + o + dI + dJ);
#pragma unroll 2
                for (int k = kbeg; k < kend; ++k) {
                    float nw00, nw10, nw01, nw11, nm;
                    int no;
                    GEOM(k + 1, nw00, nw10, nw01, nw11, nm, no);
                    float4 N00 = *(const float4*)(basep + no);
                    float4 N10 = *(const float4*)(basep + no + dI);
                    float4 N01 = *(const float4*)(basep + no + dJ);
                    float4 N11 = *(const float4*)(basep + no + dI + dJ);
                    float v0 = w00 * L00.x + w10 * L10.x + w01 * L01.x + w11 * L11.x;
                    float v1 = w00 * L00.y + w10 * L10.y + w01 * L01.y + w11 * L11.y;
                    float v2 = w00 * L00.z + w10 * L10.z + w01 * L01.z + w11 * L11.z;
                    float v3 = w00 * L00.w + w10 * L10.w + w01 * L01.w + w11 * L11.w;
                    sums[0] = __fadd_rn(sums[0], __fmul_rn(v0, m));
                    sums[1] = __fadd_rn(sums[1], __fmul_rn(v1, m));
                    sums[2] = __fadd_rn(sums[2], __fmul_rn(v2, m));
                    sums[3] = __fadd_rn(sums[3], __fmul_rn(v3, m));
                    w00 = nw00; w10 = nw10; w01 = nw01; w11 = nw11; m = nm;
                    L00 = N00; L10 = N10; L01 = N01; L11 = N11;
                }
                float v0 = w00 * L00.x + w10 * L10.x + w01 * L01.x + w11 * L11.x;
                float v1 = w00 * L00.y + w10 * L10.y + w01 * L01.y + w11 * L11.y;
                float v2 = w00 * L00.z + w10 * L10.z + w01 * L01.z + w11 * L11.z;
                float v3 = w00 * L00.w + w10 * L10.w + w01 * L01.w + w11 * L11.w;
                sums[0] = __fadd_rn(sums[0], __fmul_rn(v0, m));
                sums[1] = __fadd_rn(sums[1], __fmul_rn(v1, m));
                sums[2] = __fadd_rn(sums[2], __fmul_rn(v2, m));
                sums[3] = __fadd_rn(sums[3], __fmul_rn(v3, m));
            }
        }
    }

    if (half == 1) {
#pragma unroll
        for (int s = 0; s < 4; ++s) part[s][r] = sums[s];
    }
    __syncthreads();
    if (half == 0 && active) {
#pragma unroll
        for (int s = 0; s < 4; ++s) {
            float proj = __fmul_rn(__fadd_rn(sums[s], part[s][r]), 2.0f);  // * STEP
            int sl = i0 + s;
            int idx = (sl * NUM_PHI + phi) * NUM_RAD + r;
            float ex = __fadd_rn(__fmul_rn(mult[idx], proj), contam[idx]);
            float zval = __fmul_rn(mult[idx], __fdiv_rn(data[idx], ex));
            zt[(phi * NUM_RAD + r) * N0 + sl] = zval;
        }
    }
}

// ---------------- adjoint projection, gather form, branch-free ----------------
// grid (ceil(NPIX/256), 19): thread = pixel, blockIdx.y = phi-chunk (uniform).
// Per p: compute 4 j-candidate weights with predicated selects (tent identity,
// bit-identical to the reference select chain), then 16 unconditional float4
// loads batched before the FMA block -> full MLP, zero divergence.
__global__ __launch_bounds__(256, 4)
void backproject(const float* __restrict__ zt, const float* __restrict__ cosb,
                 const float* __restrict__ sinb, const float* __restrict__ rvb,
                 float* __restrict__ bp) {
    int pix = blockIdx.x * 256 + threadIdx.x;
    if (pix >= NPIX) return;
    int pc = blockIdx.y;
    int i1 = pix / N2;
    int i2 = pix - i1 * N2;
    float X1 = 2.f * (float)i1 - 199.f;   // ORG1 + i1*VOX (exact)
    float X2 = 2.f * (float)i2 - 199.f;
    float i1f = (float)i1, i2f = (float)i2;
    float acc[N0];
#pragma unroll
    for (int i0 = 0; i0 < N0; ++i0) acc[i0] = 0.f;

    int p_end = pc * BP_CHUNK + BP_CHUNK;
    for (int p = pc * BP_CHUNK; p < p_end; ++p) {
        float c = cosb[p], sp = sinb[p];
        float tp = c * X1 + sp * X2;      // candidate location only
        float rp = c * X2 - sp * X1;
        int j0 = (int)floorf((rp + 200.f) * 0.555f);   // 222/400
        int k0 = (int)floorf((tp + 350.f) * 0.5f);

        float wv[4];
        int jc4[4];
#pragma unroll
        for (int dj = 0; dj < 4; ++dj) {
            int j = j0 - 1 + dj;
            bool jvalid = (j >= 0) & (j <= NUM_RAD - 1);
            int jc = min(max(j, 0), NUM_RAD - 1);
            jc4[dj] = jc;
            float rv = rvb[jc];
            float A = __fmul_rn(rv, -sp);
            float B = __fmul_rn(rv, c);
            float w = 0.f;
#pragma unroll
            for (int dk = 0; dk < 4; ++dk) {
                int k = k0 - 1 + dk;
                bool kvalid = (k >= 0) & (k <= NUM_T - 1);
                float tv = (float)(2 * k - 350);
                // EXACT same op sequence as forward -> identical ix/iy/validity
                float ix = __fmul_rn(__fsub_rn(__fadd_rn(A, __fmul_rn(tv, c)), ORG1F), 0.5f);
                float iy = __fmul_rn(__fsub_rn(__fadd_rn(B, __fmul_rn(tv, sp)), ORG2F), 0.5f);
                bool valid = kvalid & (ix >= 0.f) & (ix <= 199.f) & (iy >= 0.f) & (iy <= 199.f);
                // tent form == reference's floor/select chain (Sterbenz-exact)
                float wx = fmaxf(0.f, __fsub_rn(1.f, fabsf(__fsub_rn(ix, i1f))));
                float wy = fmaxf(0.f, __fsub_rn(1.f, fabsf(__fsub_rn(iy, i2f))));
                w += valid ? __fmul_rn(wx, wy) : 0.f;
            }
            wv[dj] = jvalid ? w : 0.f;
        }

        // batched unconditional loads (16 float4 in flight)
        float4 Z[4][4];
#pragma unroll
        for (int dj = 0; dj < 4; ++dj) {
            const float4* zp4 = (const float4*)(zt + (p * NUM_RAD + jc4[dj]) * N0);
            Z[dj][0] = zp4[0]; Z[dj][1] = zp4[1]; Z[dj][2] = zp4[2]; Z[dj][3] = zp4[3];
        }
#pragma unroll
        for (int dj = 0; dj < 4; ++dj) {
            float w = wv[dj];
            acc[0]  += w * Z[dj][0].x;  acc[1]  += w * Z[dj][0].y;
            acc[2]  += w * Z[dj][0].z;  acc[3]  += w * Z[dj][0].w;
            acc[4]  += w * Z[dj][1].x;  acc[5]  += w * Z[dj][1].y;
            acc[6]  += w * Z[dj][1].z;  acc[7]  += w * Z[dj][1].w;
            acc[8]  += w * Z[dj][2].x;  acc[9]  += w * Z[dj][2].y;
            acc[10] += w * Z[dj][2].z;  acc[11] += w * Z[dj][2].w;
            acc[12] += w * Z[dj][3].x;  acc[13] += w * Z[dj][3].y;
            acc[14] += w * Z[dj][3].z;  acc[15] += w * Z[dj][3].w;
        }
    }
#pragma unroll
    for (int i0 = 0; i0 < N0; ++i0)
        atomicAdd(&bp[i0 * NPIX + pix], acc[i0] * 2.0f);  // * STEP
}

extern "C" void kernel_launch(void* const* d_in, const int* in_sizes, int n_in,
                              void* d_out, int out_size, void* d_ws, size_t ws_size,
                              hipStream_t stream) {
    const float* x      = (const float*)d_in[0];
    const float* data   = (const float*)d_in[1];
    const float* contam = (const float*)d_in[2];
    const float* mult   = (const float*)d_in[3];
    const float* sens   = (const float*)d_in[4];
    float* out = (float*)d_out;

    float* W    = (float*)d_ws;
    float* s    = W;                        // 640000 (smoothed; later reused as bp)
    float* tmp  = W + NVOX;                 // 640000
    float* bp2  = W + 2 * NVOX;             // 640000
    float* zt   = W + 3 * NVOX;             // 677920
    float* P    = W + 3 * NVOX + NSINO;     // 646416
    float* PT   = P + 4 * QSTRIDE;          // 646416
    float* cosb = PT + 4 * QSTRIDE;
    float* sinb = cosb + NUM_PHI;
    float* rvb  = sinb + NUM_PHI;
    float* gwb  = rvb + NUM_RAD;

    hipLaunchKernelGGL(init_consts, dim3(1), dim3(256), 0, stream, cosb, sinb, rvb, gwb);

    // gauss3 forward: x -> s (axis0), s -> tmp (axis1), tmp -> {P, PT} (axis2 quad dual-store)
    int nb = (NVOX + 255) / 256;
    hipLaunchKernelGGL(smooth_fwd, dim3(nb), dim3(256), 0, stream, x,   s,   gwb, N0, NPIX);
    hipLaunchKernelGGL(smooth_fwd, dim3(nb), dim3(256), 0, stream, s,   tmp, gwb, N1, N2);
    hipLaunchKernelGGL(smooth_fwd2_quad, dim3(nb), dim3(256), 0, stream, tmp, P, PT, gwb);

    // forward project + ratio (writes zt): 4 slices/thread via float4, 2 t-halves/block
    hipLaunchKernelGGL(project_ratio, dim3(NUM_PHI, N0 / 4), dim3(256, 2), 0, stream,
                       P, PT, data, contam, mult, cosb, sinb, rvb, zt);

    // backproject (gather) into bp (reuse s)
    float* bp = s;
    hipMemsetAsync(bp, 0, NVOX * sizeof(float), stream);
    int nbp = (NPIX + 255) / 256;
    hipLaunchKernelGGL(backproject, dim3(nbp, BP_NCH), dim3(256), 0, stream,
                       zt, cosb, sinb, rvb, bp);

    // gauss3 adjoint: bp -> tmp (axis2^T), tmp -> bp2 (axis1^T), bp2 -> out (axis0^T fused final)
    hipLaunchKernelGGL(smooth_adj, dim3(nb), dim3(256), 0, stream, bp,  tmp, gwb, N2, 1);
    hipLaunchKernelGGL(smooth_adj, dim3(nb), dim3(256), 0, stream, tmp, bp2, gwb, N1, N2);
    hipLaunchKernelGGL(smooth_adj0_final, dim3(nb), dim3(256), 0, stream, bp2, x, sens, gwb, out);
}